// Round 4
// baseline (2460.782 us; speedup 1.0000x reference)
//
#include <hip/hip_runtime.h>
#include <cstdint>
#include <cstddef>

typedef float        f32x4  __attribute__((ext_vector_type(4)));
typedef __bf16       bf16x8 __attribute__((ext_vector_type(8)));
typedef unsigned int u32x4  __attribute__((ext_vector_type(4)));
typedef unsigned int u32x2  __attribute__((ext_vector_type(2)));

// ---------------- problem dims ----------------
static constexpr int HID   = 1536;
static constexpr int NHEAD = 12;
static constexpr int HD    = 128;
static constexpr int NQKV  = 10752;   // 3*HID + 4*HID
static constexpr int CATK  = 7680;    // HID + 4*HID
static constexpr int LX    = 4352;    // text 256 + 4096 image
static constexpr int LC2   = 4116;    // 20 concepts + 4096 image
static constexpr int NCON  = 20;
static constexpr int NSPL2 = 8;       // k-split for block-2 attention

// q pre-scale: 1/sqrt(128) * log2(e)  (softmax computed in exp2 domain)
static constexpr float QSCL = 0.08838834764831845f * 1.4426950408889634f;

// ---------------- workspace layout (bytes) ----------------
static constexpr size_t OFF_MVEC = 0;                          // 4608 f32
static constexpr size_t OFF_W1B  = 18432;                      // 10752x1536 bf16
static constexpr size_t OFF_W2B  = OFF_W1B  + 33030144ull;     // 1536x7680 bf16
static constexpr size_t OFF_XM1  = OFF_W2B  + 23592960ull;     // 4352x1536 bf16 (later aliased by qh1)
static constexpr size_t OFF_QH1  = OFF_XM1;                    // [12][4352][128] bf16
static constexpr size_t OFF_QKV1 = OFF_XM1  + 13369344ull;     // 4352x3072 bf16 (q,k raw)
static constexpr size_t OFF_KH1  = OFF_QKV1 + 26738688ull;     // [12][4352][128]
static constexpr size_t OFF_VH1  = OFF_KH1  + 13369344ull;     // [12][128][4352] (transposed)
static constexpr size_t OFF_CAT1 = OFF_VH1  + 13369344ull;     // 4352x7680 bf16
// block-2 scratch aliased inside cat1 (cat1 dead after GEMM2 of block 1):
static constexpr size_t OFF_XM2  = OFF_CAT1;                   // 64x1536 bf16
static constexpr size_t OFF_QKV2 = OFF_XM2  + 196608ull;       // 32x3072 bf16
static constexpr size_t OFF_VH2S = OFF_QKV2 + 196608ull;       // [12][128][32]
static constexpr size_t OFF_QH2  = OFF_VH2S + 98304ull;        // [12][64][128]
static constexpr size_t OFF_KH2  = OFF_QH2  + 196608ull;       // [12][4116][128]
static constexpr size_t OFF_CAT2 = OFF_KH2  + 12644352ull;     // 32x7680 bf16
static constexpr size_t OFF_OPAR = OFF_CAT2 + 491520ull;       // [8][12][20][128] f32 partial O
static constexpr size_t OFF_LPAR = OFF_OPAR + 983040ull;       // [8][12][20] f32 partial l
// all block-2 scratch ends well inside cat1's 66,846,720 bytes.
// total required: OFF_CAT1 + 66846720 = 190,334,976 bytes (unchanged from r1-r3)

// ---------------- small kernels ----------------

__global__ __launch_bounds__(256) void f2b_kernel(const float* __restrict__ in,
                                                  __bf16* __restrict__ out, int n4)
{
  int i = blockIdx.x * 256 + threadIdx.x;
  if (i >= n4) return;
  f32x4 v = *((const f32x4*)in + i);
  union { __bf16 h[4]; u32x2 u; } cv;
  cv.h[0] = (__bf16)v[0]; cv.h[1] = (__bf16)v[1];
  cv.h[2] = (__bf16)v[2]; cv.h[3] = (__bf16)v[3];
  *((u32x2*)out + i) = cv.u;
}

// m = silu(vec) @ mod_w.T + mod_b   (one wave per output)
__global__ __launch_bounds__(256) void mod_kernel(const float* __restrict__ vec,
                                                  const float* __restrict__ mod_w,
                                                  const float* __restrict__ mod_b,
                                                  float* __restrict__ m)
{
  int o = blockIdx.x * 4 + (threadIdx.x >> 6);
  int lane = threadIdx.x & 63;
  float s = 0.0f;
  for (int k = lane; k < HID; k += 64) {
    float v = vec[k];
    float sv = v / (1.0f + expf(-v));
    s += sv * mod_w[(size_t)o * HID + k];
  }
  #pragma unroll
  for (int msk = 32; msk; msk >>= 1) s += __shfl_xor(s, msk);
  if (lane == 0) m[o] = s + mod_b[o];
}

__device__ __forceinline__ float block_sum256(float v, float* red)
{
  #pragma unroll
  for (int msk = 32; msk; msk >>= 1) v += __shfl_xor(v, msk);
  int w = threadIdx.x >> 6;
  if ((threadIdx.x & 63) == 0) red[w] = v;
  __syncthreads();
  float s = red[0] + red[1] + red[2] + red[3];
  __syncthreads();
  return s;
}

// xm = (1+scale)*layernorm(x) + shift, bf16 out. one block per row.
// scal_init: 24-float scratch (q/k norm maxima) zeroed by block 0.
__global__ __launch_bounds__(256) void ln_mod_kernel(const float* __restrict__ x,
                                                     const float* __restrict__ mvec,
                                                     __bf16* __restrict__ out,
                                                     float* __restrict__ scal_init)
{
  __shared__ float red[4];
  if (blockIdx.x == 0 && threadIdx.x < 24) scal_init[threadIdx.x] = 0.0f;
  size_t row = blockIdx.x;
  const float* xr = x + row * HID;
  float v[6]; float s = 0.0f;
  #pragma unroll
  for (int i = 0; i < 6; i++) { v[i] = xr[threadIdx.x + i * 256]; s += v[i]; }
  float mu = block_sum256(s, red) * (1.0f / HID);
  float s2 = 0.0f;
  #pragma unroll
  for (int i = 0; i < 6; i++) { float d = v[i] - mu; s2 += d * d; }
  float var = block_sum256(s2, red) * (1.0f / HID);
  float rinv = rsqrtf(var + 1e-6f);
  #pragma unroll
  for (int i = 0; i < 6; i++) {
    int h = threadIdx.x + i * 256;
    float xm = (v[i] - mu) * rinv;
    xm = (1.0f + mvec[HID + h]) * xm + mvec[h];
    out[row * HID + h] = (__bf16)xm;
  }
}

// ---------------- GEMM (B^T layout): C[m,n] = sum_k A[m,k]*B[n,k] ----------------
// 128x128 tile, BK=64, global_load_lds width-16 staging (m97 structure).
typedef __attribute__((address_space(3))) unsigned int  lds_u32;
typedef const __attribute__((address_space(1))) unsigned int g_u32;

template<int MODE>
__global__ __launch_bounds__(256) void gemm_bt(const __bf16* __restrict__ A,
                                               const __bf16* __restrict__ B,
                                               int M, int K,
                                               const float* __restrict__ bias,
                                               __bf16* __restrict__ qkv_out,
                                               __bf16* __restrict__ cat_out,
                                               __bf16* __restrict__ vh_out, int vkeys,
                                               const float* __restrict__ res,
                                               const float* __restrict__ gate,
                                               float* __restrict__ out)
{
  const int tid = threadIdx.x;
  const int lane = tid & 63, wave = tid >> 6;
  const int quad = lane >> 4, l16 = lane & 15;
  const int m0 = blockIdx.y * 128, n0 = blockIdx.x * 128;
  const int wm = (wave & 1) * 64, wn = (wave >> 1) * 64;

  __shared__ __bf16 AsF[128 * 64];   // unpadded: required by global_load_lds
  __shared__ __bf16 BsF[128 * 64];

  const int srow = lane >> 3;            // 0..7
  const int scol = (lane & 7) * 8;       // 0..56 (elems)

  const f32x4 fzero = {0.0f, 0.0f, 0.0f, 0.0f};
  f32x4 acc[4][4];
  #pragma unroll
  for (int i = 0; i < 4; i++)
    #pragma unroll
    for (int j = 0; j < 4; j++) acc[i][j] = fzero;

  for (int k0 = 0; k0 < K; k0 += 64) {
    __syncthreads();
    #pragma unroll
    for (int j = 0; j < 4; j++) {
      int chunk = wave * 4 + j;          // 16 chunks of 8 rows each
      const __bf16* ga = A + (size_t)(m0 + chunk * 8 + srow) * K + k0 + scol;
      __builtin_amdgcn_global_load_lds((g_u32*)ga, (lds_u32*)(AsF + chunk * 512), 16, 0, 0);
      const __bf16* gb = B + (size_t)(n0 + chunk * 8 + srow) * K + k0 + scol;
      __builtin_amdgcn_global_load_lds((g_u32*)gb, (lds_u32*)(BsF + chunk * 512), 16, 0, 0);
    }
    __syncthreads();
    #pragma unroll
    for (int kk = 0; kk < 64; kk += 32) {
      bf16x8 af[4], bfr[4];
      #pragma unroll
      for (int i = 0; i < 4; i++) af[i]  = *(const bf16x8*)&AsF[(wm + i * 16 + l16) * 64 + kk + quad * 8];
      #pragma unroll
      for (int j = 0; j < 4; j++) bfr[j] = *(const bf16x8*)&BsF[(wn + j * 16 + l16) * 64 + kk + quad * 8];
      #pragma unroll
      for (int i = 0; i < 4; i++)
        #pragma unroll
        for (int j = 0; j < 4; j++)
          acc[i][j] = __builtin_amdgcn_mfma_f32_16x16x32_bf16(af[i], bfr[j], acc[i][j], 0, 0, 0);
    }
  }

  #pragma unroll
  for (int i = 0; i < 4; i++) {
    #pragma unroll
    for (int r = 0; r < 4; r++) {
      int gm = m0 + wm + i * 16 + quad * 4 + r;
      if (gm >= M) continue;
      #pragma unroll
      for (int j = 0; j < 4; j++) {
        int gn = n0 + wn + j * 16 + l16;
        float v = acc[i][j][r] + bias[gn];
        if constexpr (MODE == 0) {
          if (gn < 3072) {                 // q,k raw
            qkv_out[(size_t)gm * 3072 + gn] = (__bf16)v;
          } else if (gn < 4608) {          // v -> transposed [head*128+d][key]
            vh_out[(size_t)(gn - 3072) * vkeys + gm] = (__bf16)v;
          } else {                         // mlp -> gelu -> cat cols [1536,7680)
            float g = 0.5f * v * (1.0f + tanhf(0.7978845608028654f * (v + 0.044715f * v * v * v)));
            cat_out[(size_t)gm * CATK + (gn - 3072)] = (__bf16)g;
          }
        } else {
          out[(size_t)gm * HID + gn] = res[(size_t)gm * HID + gn] + gate[gn] * v;
        }
      }
    }
  }
}

// ---------------- q/k rmsnorm + rope preprocessing ----------------
// also accumulates per-head max row norms (scal[h]=q, scal[12+h]=k) for the
// fixed-softmax-bound trick (Cauchy-Schwarz: s <= |q||k|).
__global__ __launch_bounds__(256) void qk_prep(const __bf16* __restrict__ src0, int rows0,
                                               const __bf16* __restrict__ src1, int off1,
                                               int total_rows, int q_rows,
                                               const float* __restrict__ pe,
                                               const float* __restrict__ qscale,
                                               const float* __restrict__ kscale,
                                               __bf16* __restrict__ qh, int q_stride,
                                               __bf16* __restrict__ kh, int k_stride,
                                               float* __restrict__ scal)
{
  int wid = blockIdx.x * 4 + (threadIdx.x >> 6);
  int lane = threadIdx.x & 63;
  int r = wid / NHEAD, h = wid - (wid / NHEAD) * NHEAD;
  if (r >= total_rows) return;
  const __bf16* src = (r < rows0) ? (src0 + (size_t)r * 3072)
                                  : (src1 + (size_t)(r + off1) * 3072);
  const float* pep = pe + ((size_t)r * 64 + lane) * 4;
  float e00 = pep[0], e01 = pep[1], e10 = pep[2], e11 = pep[3];

  { // k
    const __bf16* p = src + HID + h * HD + 2 * lane;
    float a = (float)p[0], b = (float)p[1];
    float ss = a * a + b * b;
    #pragma unroll
    for (int msk = 32; msk; msk >>= 1) ss += __shfl_xor(ss, msk);
    float rinv = rsqrtf(ss * (1.0f / HD) + 1e-6f);
    a *= rinv * kscale[2 * lane]; b *= rinv * kscale[2 * lane + 1];
    float ra = e00 * a + e01 * b, rb = e10 * a + e11 * b;
    __bf16* o = kh + ((size_t)h * k_stride + r) * HD + 2 * lane;
    o[0] = (__bf16)ra; o[1] = (__bf16)rb;
    float nr = ra * ra + rb * rb;
    #pragma unroll
    for (int msk = 32; msk; msk >>= 1) nr += __shfl_xor(nr, msk);
    if (lane == 0) atomicMax((int*)&scal[12 + h], __float_as_int(sqrtf(nr)));
  }
  if (r < q_rows) { // q (with folded softmax scale, exp2 domain)
    const __bf16* p = src + h * HD + 2 * lane;
    float a = (float)p[0], b = (float)p[1];
    float ss = a * a + b * b;
    #pragma unroll
    for (int msk = 32; msk; msk >>= 1) ss += __shfl_xor(ss, msk);
    float rinv = rsqrtf(ss * (1.0f / HD) + 1e-6f);
    a *= rinv * qscale[2 * lane]; b *= rinv * qscale[2 * lane + 1];
    float ra = (e00 * a + e01 * b) * QSCL, rb = (e10 * a + e11 * b) * QSCL;
    __bf16* o = qh + ((size_t)h * q_stride + r) * HD + 2 * lane;
    o[0] = (__bf16)ra; o[1] = (__bf16)rb;
    float nr = ra * ra + rb * rb;
    #pragma unroll
    for (int msk = 32; msk; msk >>= 1) nr += __shfl_xor(nr, msk);
    if (lane == 0) atomicMax((int*)&scal[h], __float_as_int(sqrtf(nr)));
  }
}

// ---------------- flash attention v4: fixed softmax bound, 32q/wave ----------------
// 512 threads = 8 waves: qsub=wave>>1 (4), kg=wave&1 (2). Block covers 128 q rows
// of one head; 64-key LDS tiles; each wave: 32 q (2 subtiles) x 32 keys (kg half).
// p = exp2(s - Mh) with Mh = max|q| * max|k| per head (no online max, no rescale,
// no cross-lane reductions). l via ones-MFMA. kg halves merged through LDS at end.
// NSPLIT>1: keys strided across blocks, partial (o,l) written to opart/lpart.
template<int NSPLIT>
__global__ __launch_bounds__(512, 2) void attn_kernel(const __bf16* __restrict__ qh,
                                                      const __bf16* __restrict__ kh,
                                                      const __bf16* __restrict__ vA, int vA_stride,
                                                      const __bf16* __restrict__ vB, int vB_stride,
                                                      int v_boff, int v_split,
                                                      int Lq, int Lk, int q_stride, int k_stride,
                                                      int nqt,
                                                      const float* __restrict__ scal,
                                                      __bf16* __restrict__ cat_out,
                                                      float* __restrict__ opart,
                                                      float* __restrict__ lpart)
{
  const int tid = threadIdx.x, lane = tid & 63, wave = tid >> 6;
  const int quad = lane >> 4, l16 = lane & 15;
  const int qsub = wave >> 1, kg = wave & 1;
  const int sp = blockIdx.x % NSPLIT;
  const int hq = blockIdx.x / NSPLIT;
  const int head = hq / nqt, qt = hq - head * nqt;
  const int q0 = qt * 128 + qsub * 32;

  __shared__ __align__(16) unsigned char lds_raw[56320];
  __bf16 (*Ks)[136]        = (__bf16(*)[136])(lds_raw);                 // [64][136]  17408
  __bf16 (*Vt)[72]         = (__bf16(*)[72])(lds_raw + 17408);          // [128][72]  18432
  __bf16 (*Ps)[2][16][40]  = (__bf16(*)[2][16][40])(lds_raw + 35840);   // [8][2][16][40] 20480
  float*  Of               = (float*)lds_raw;                           // merge alias [64][132]
  float*  Lf               = (float*)(lds_raw + 33792);                 // merge alias [64]

  const f32x4 fzero = {0.0f, 0.0f, 0.0f, 0.0f};
  const u32x4 uzero = {0, 0, 0, 0};

  const float Mh = scal[head] * scal[12 + head] * 1.02f;   // >= any logit (C-S + bf16 slack)

  bf16x8 ones;
  #pragma unroll
  for (int e = 0; e < 8; e++) ones[e] = (__bf16)1.0f;

  bf16x8 qf[2][4];
  #pragma unroll
  for (int st = 0; st < 2; st++) {
    int qrow = q0 + st * 16 + l16;
    if (qrow < Lq) {
      const __bf16* qp = qh + ((size_t)head * q_stride + qrow) * HD + quad * 8;
      #pragma unroll
      for (int c = 0; c < 4; c++) qf[st][c] = *(const bf16x8*)(qp + c * 32);
    } else {
      #pragma unroll
      for (int c = 0; c < 4; c++) qf[st][c] = __builtin_bit_cast(bf16x8, uzero);
    }
  }
  f32x4 o[2][8];
  #pragma unroll
  for (int st = 0; st < 2; st++)
    #pragma unroll
    for (int d = 0; d < 8; d++) o[st][d] = fzero;
  f32x4 l_acc[2] = {fzero, fzero};

  // staging coords (512 threads): K 64x128 as 2 chunks, V 128x64 as 2 chunks
  const int krowA = tid >> 4, kcolA = (tid & 15) * 8;   // rows 0..31 (+32)
  const int vdimA = tid >> 3, vkcA  = (tid & 7) * 8;    // dims 0..63 (+64)

  const __bf16* khb = kh + (size_t)head * k_stride * HD;
  const __bf16* vaB = vA + (size_t)head * HD * vA_stride;
  const __bf16* vbB = vB + (size_t)head * HD * vB_stride + v_boff;

  auto vload = [&](int dim, int kb) -> u32x4 {
    u32x4 vd = uzero;
    if (kb < Lk) {
      if (kb + 8 <= v_split) {
        vd = *(const u32x4*)(vaB + (size_t)dim * vA_stride + kb);
      } else if (kb >= v_split && kb + 8 <= Lk) {
        vd = *(const u32x4*)(vbB + (size_t)dim * vB_stride + kb);
      } else {
        __bf16* ve = (__bf16*)&vd;
        #pragma unroll
        for (int e = 0; e < 8; e++) {
          int key = kb + e;
          if (key < Lk)
            ve[e] = (key < v_split) ? vaB[(size_t)dim * vA_stride + key]
                                    : vbB[(size_t)dim * vB_stride + key];
        }
      }
    }
    return vd;
  };
  auto kload = [&](int kr, int col) -> u32x4 {
    return (kr < Lk) ? *(const u32x4*)(khb + (size_t)kr * HD + col) : uzero;
  };

  const int nkt = (Lk + 63) >> 6;
  u32x4 pk0 = kload(sp * 64 + krowA, kcolA);
  u32x4 pk1 = kload(sp * 64 + krowA + 32, kcolA);
  u32x4 pv0 = vload(vdimA, sp * 64 + vkcA);
  u32x4 pv1 = vload(vdimA + 64, sp * 64 + vkcA);

  for (int t = sp; t < nkt; t += NSPLIT) {
    const int kt0 = t * 64;
    __syncthreads();                       // previous tile's readers done
    *(u32x4*)&Ks[krowA][kcolA]      = pk0;
    *(u32x4*)&Ks[krowA + 32][kcolA] = pk1;
    *(u32x4*)&Vt[vdimA][vkcA]       = pv0;
    *(u32x4*)&Vt[vdimA + 64][vkcA]  = pv1;
    const int tn = t + NSPLIT;
    if (tn < nkt) {                        // prefetch next tile
      const int nt0 = tn * 64;
      pk0 = kload(nt0 + krowA, kcolA);
      pk1 = kload(nt0 + krowA + 32, kcolA);
      pv0 = vload(vdimA, nt0 + vkcA);
      pv1 = vload(vdimA + 64, nt0 + vkcA);
    }
    __syncthreads();                       // tile staged

    // S = Q K^T : K-frags read once, feed both q-subtiles
    f32x4 s[2][2] = {{fzero, fzero}, {fzero, fzero}};
    #pragma unroll
    for (int nt = 0; nt < 2; nt++) {
      #pragma unroll
      for (int c = 0; c < 4; c++) {
        bf16x8 kb = *(const bf16x8*)&Ks[kg * 32 + nt * 16 + l16][c * 32 + quad * 8];
        s[0][nt] = __builtin_amdgcn_mfma_f32_16x16x32_bf16(qf[0][c], kb, s[0][nt], 0, 0, 0);
        s[1][nt] = __builtin_amdgcn_mfma_f32_16x16x32_bf16(qf[1][c], kb, s[1][nt], 0, 0, 0);
      }
    }

    // p = exp2(s - Mh); masked keys -> 0. No cross-lane reduction needed.
    #pragma unroll
    for (int st = 0; st < 2; st++) {
      #pragma unroll
      for (int nt = 0; nt < 2; nt++) {
        bool oob = (kt0 + kg * 32 + nt * 16 + l16) >= Lk;
        #pragma unroll
        for (int r = 0; r < 4; r++) {
          float p = oob ? 0.0f : exp2f(s[st][nt][r] - Mh);
          Ps[wave][st][quad * 4 + r][nt * 16 + l16] = (__bf16)p;
        }
      }
    }
    // no barrier: Ps is wave-local

    bf16x8 pf0 = *(const bf16x8*)&Ps[wave][0][l16][quad * 8];
    bf16x8 pf1 = *(const bf16x8*)&Ps[wave][1][l16][quad * 8];
    l_acc[0] = __builtin_amdgcn_mfma_f32_16x16x32_bf16(pf0, ones, l_acc[0], 0, 0, 0);
    l_acc[1] = __builtin_amdgcn_mfma_f32_16x16x32_bf16(pf1, ones, l_acc[1], 0, 0, 0);
    #pragma unroll
    for (int d = 0; d < 8; d++) {
      bf16x8 bv = *(const bf16x8*)&Vt[d * 16 + l16][kg * 32 + quad * 8];
      o[0][d] = __builtin_amdgcn_mfma_f32_16x16x32_bf16(pf0, bv, o[0][d], 0, 0, 0);
      o[1][d] = __builtin_amdgcn_mfma_f32_16x16x32_bf16(pf1, bv, o[1][d], 0, 0, 0);
    }
  }

  // ---- merge kg halves (fixed M: plain sums). Two phases to fit LDS. ----
  #pragma unroll
  for (int ph = 0; ph < 2; ph++) {
    __syncthreads();
    if (kg == 0 && (qsub >> 1) == ph) {
      #pragma unroll
      for (int st = 0; st < 2; st++)
        #pragma unroll
        for (int r = 0; r < 4; r++) {
          int lrow = (qsub & 1) * 32 + st * 16 + quad * 4 + r;
          if (l16 == 0) Lf[lrow] = l_acc[st][r];
          #pragma unroll
          for (int d = 0; d < 8; d++)
            Of[(size_t)lrow * 132 + d * 16 + l16] = o[st][d][r];
        }
    }
    __syncthreads();
    if (kg == 1 && (qsub >> 1) == ph) {
      #pragma unroll
      for (int st = 0; st < 2; st++)
        #pragma unroll
        for (int r = 0; r < 4; r++) {
          int lrow = (qsub & 1) * 32 + st * 16 + quad * 4 + r;
          int qrow = q0 + st * 16 + quad * 4 + r;
          if (qrow >= Lq) continue;
          float lsum = Lf[lrow] + l_acc[st][r];
          if constexpr (NSPLIT == 1) {
            float inv = 1.0f / lsum;
            #pragma unroll
            for (int d = 0; d < 8; d++) {
              float v = Of[(size_t)lrow * 132 + d * 16 + l16] + o[st][d][r];
              cat_out[(size_t)qrow * CATK + head * HD + d * 16 + l16] = (__bf16)(v * inv);
            }
          } else {
            if (l16 == 0) lpart[(sp * NHEAD + head) * NCON + qrow] = lsum;
            #pragma unroll
            for (int d = 0; d < 8; d++) {
              float v = Of[(size_t)lrow * 132 + d * 16 + l16] + o[st][d][r];
              opart[(size_t)((sp * NHEAD + head) * NCON + qrow) * HD + d * 16 + l16] = v;
            }
          }
        }
    }
  }
}

// merge the NSPL2 key-split partials of block-2 attention -> cat2 cols [0,1536)
__global__ __launch_bounds__(256) void attn2_reduce(const float* __restrict__ opart,
                                                    const float* __restrict__ lpart,
                                                    __bf16* __restrict__ cat2)
{
  int idx = blockIdx.x * 256 + threadIdx.x;
  if (idx >= NCON * HID) return;
  int row = idx / HID, col = idx - row * HID;
  int head = col >> 7, d = col & 127;
  float osum = 0.0f, lsum = 0.0f;
  #pragma unroll
  for (int sp2 = 0; sp2 < NSPL2; sp2++) {
    osum += opart[(size_t)((sp2 * NHEAD + head) * NCON + row) * HD + d];
    lsum += lpart[(sp2 * NHEAD + head) * NCON + row];
  }
  cat2[(size_t)row * CATK + head * HD + d] = (__bf16)(osum / lsum);
}

// ---------------- launch ----------------
extern "C" void kernel_launch(void* const* d_in, const int* in_sizes, int n_in,
                              void* d_out, int out_size, void* d_ws, size_t ws_size,
                              hipStream_t stream)
{
  const float* x   = (const float*)d_in[0];
  const float* con = (const float*)d_in[1];
  const float* vec = (const float*)d_in[2];
  const float* pe  = (const float*)d_in[3];
  const float* cpe = (const float*)d_in[4];
  const float* w1  = (const float*)d_in[5];
  const float* b1  = (const float*)d_in[6];
  const float* w2  = (const float*)d_in[7];
  const float* b2  = (const float*)d_in[8];
  const float* qsc = (const float*)d_in[9];
  const float* ksc = (const float*)d_in[10];
  const float* mw  = (const float*)d_in[11];
  const float* mb  = (const float*)d_in[12];
  float* out = (float*)d_out;

  char* ws = (char*)d_ws;
  float*  mvec = (float*)(ws + OFF_MVEC);
  __bf16* w1b  = (__bf16*)(ws + OFF_W1B);
  __bf16* w2b  = (__bf16*)(ws + OFF_W2B);
  __bf16* xm1  = (__bf16*)(ws + OFF_XM1);
  __bf16* qh1  = (__bf16*)(ws + OFF_QH1);
  __bf16* qkv1 = (__bf16*)(ws + OFF_QKV1);
  __bf16* kh1  = (__bf16*)(ws + OFF_KH1);
  __bf16* vh1  = (__bf16*)(ws + OFF_VH1);
  __bf16* cat1 = (__bf16*)(ws + OFF_CAT1);
  __bf16* xm2  = (__bf16*)(ws + OFF_XM2);
  __bf16* qkv2 = (__bf16*)(ws + OFF_QKV2);
  __bf16* vh2s = (__bf16*)(ws + OFF_VH2S);
  __bf16* qh2  = (__bf16*)(ws + OFF_QH2);
  __bf16* kh2  = (__bf16*)(ws + OFF_KH2);
  __bf16* cat2 = (__bf16*)(ws + OFF_CAT2);
  float*  opar = (float*)(ws + OFF_OPAR);
  float*  lpar = (float*)(ws + OFF_LPAR);

  // norm-bound scratch (24 floats each) lives in d_out: scal1 in the x-output
  // region (overwritten by gemm2-1 AFTER attn1), scal2 in the concept-output
  // region (overwritten by gemm2-2 AFTER attn2).
  float* scal1 = out;
  float* scal2 = out + (size_t)LX * HID;

  // weights -> bf16
  f2b_kernel<<<16128, 256, 0, stream>>>(w1, w1b, (NQKV * HID) / 4);
  f2b_kernel<<<11520, 256, 0, stream>>>(w2, w2b, (HID * CATK) / 4);
  // modulation vector
  mod_kernel<<<1152, 256, 0, stream>>>(vec, mw, mb, mvec);

  // ---- block 1 ----
  ln_mod_kernel<<<LX, 256, 0, stream>>>(x, mvec, xm1, scal1);
  gemm_bt<0><<<dim3(NQKV / 128, LX / 128), 256, 0, stream>>>(
      xm1, w1b, LX, HID, b1, qkv1, cat1, vh1, LX, nullptr, nullptr, nullptr);
  qk_prep<<<(LX * NHEAD) / 4, 256, 0, stream>>>(
      qkv1, LX, qkv1, 0, LX, LX, pe, qsc, ksc, qh1, LX, kh1, LX, scal1);
  attn_kernel<1><<<NHEAD * (LX / 128), 512, 0, stream>>>(
      qh1, kh1, vh1, LX, vh1, LX, 0, 0, LX, LX, LX, LX, LX / 128, scal1,
      cat1, nullptr, nullptr);
  gemm_bt<1><<<dim3(HID / 128, LX / 128), 256, 0, stream>>>(
      cat1, w2b, LX, CATK, b2, nullptr, nullptr, nullptr, 0, x, mvec + 3072, out);

  // ---- block 2 (only 20 concept queries matter; k/v of image rows reused) ----
  ln_mod_kernel<<<NCON, 256, 0, stream>>>(con, mvec, xm2, scal2);
  gemm_bt<0><<<dim3(NQKV / 128, 1), 256, 0, stream>>>(
      xm2, w1b, NCON, HID, b1, qkv2, cat2, vh2s, 32, nullptr, nullptr, nullptr);
  qk_prep<<<(LC2 * NHEAD + 3) / 4, 256, 0, stream>>>(
      qkv2, NCON, qkv1, 236, LC2, NCON, cpe, qsc, ksc, qh2, 64, kh2, LC2, scal2);
  attn_kernel<NSPL2><<<NHEAD * NSPL2, 512, 0, stream>>>(
      qh2, kh2, vh2s, 32, vh1, LX, 236, NCON, NCON, LC2, 64, LC2, 1, scal2,
      nullptr, opar, lpar);
  attn2_reduce<<<(NCON * HID + 255) / 256, 256, 0, stream>>>(opar, lpar, cat2);
  gemm_bt<1><<<dim3(HID / 128, 1), 256, 0, stream>>>(
      cat2, w2b, NCON, CATK, b2, nullptr, nullptr, nullptr, 0, con, mvec + 3072,
      out + (size_t)LX * HID);
}